// Round 4
// baseline (271.124 us; speedup 1.0000x reference)
//
#include <hip/hip_runtime.h>
#include <hip/hip_bf16.h>

typedef __bf16 bf16x8 __attribute__((ext_vector_type(8)));
typedef float  f32x4  __attribute__((ext_vector_type(4)));
typedef float  f32x16 __attribute__((ext_vector_type(16)));

typedef __attribute__((address_space(3))) unsigned int as3_u32;
typedef __attribute__((address_space(1))) unsigned int as1_u32;

__device__ __forceinline__ void gld_lds16(const void* gptr, void* lptr){
  __builtin_amdgcn_global_load_lds((const as1_u32*)gptr, (as3_u32*)lptr, 16, 0, 0);
}

// ---------------- weight convert + transpose: in[R][C] f32 -> out[C][R] bf16
__global__ __launch_bounds__(256) void transpose_cvt(const float* __restrict__ in,
                                                     __bf16* __restrict__ out, int R, int C){
  __shared__ float tile[32][33];
  const int c0 = blockIdx.x*32, r0 = blockIdx.y*32;
  const int tx = threadIdx.x, ty = threadIdx.y;
  #pragma unroll
  for (int i=0;i<32;i+=8)
    tile[ty+i][tx] = in[(size_t)(r0+ty+i)*C + c0+tx];
  __syncthreads();
  #pragma unroll
  for (int i=0;i<32;i+=8)
    out[(size_t)(c0+ty+i)*R + r0+tx] = (__bf16)tile[tx][ty+i];
}

// ---------------- layernorm: rows of 1024 f32 -> bf16
__global__ __launch_bounds__(256) void ln_kernel(const float* __restrict__ x, const float* __restrict__ g,
                                                 const float* __restrict__ b, __bf16* __restrict__ out){
  const int row = blockIdx.x, t = threadIdx.x;
  const float4 v = ((const float4*)(x + (size_t)row*1024))[t];
  float s = v.x+v.y+v.z+v.w;
  #pragma unroll
  for (int m=1;m<64;m<<=1) s += __shfl_xor(s, m);
  __shared__ float red[8];
  if ((t&63)==0) red[t>>6] = s;
  __syncthreads();
  const float mu = (red[0]+red[1]+red[2]+red[3]) * (1.f/1024.f);
  const float d0=v.x-mu, d1=v.y-mu, d2=v.z-mu, d3=v.w-mu;
  float sq = d0*d0+d1*d1+d2*d2+d3*d3;
  #pragma unroll
  for (int m=1;m<64;m<<=1) sq += __shfl_xor(sq, m);
  if ((t&63)==0) red[4+(t>>6)] = sq;
  __syncthreads();
  const float var = (red[4]+red[5]+red[6]+red[7]) * (1.f/1024.f);
  const float inv = rsqrtf(var + 1e-12f);
  const float4 gv = ((const float4*)g)[t];
  const float4 bv = ((const float4*)b)[t];
  union { __bf16 h[4]; uint2 u; } pk;
  pk.h[0]=(__bf16)(d0*inv*gv.x+bv.x); pk.h[1]=(__bf16)(d1*inv*gv.y+bv.y);
  pk.h[2]=(__bf16)(d2*inv*gv.z+bv.z); pk.h[3]=(__bf16)(d3*inv*gv.w+bv.w);
  *(uint2*)(out + (size_t)row*1024 + t*4) = pk.u;
}

// ---------------- GEMM: C[M,N] = A[M,K](bf16,row) @ Bt[N,K](bf16,row)^T + bias, fused epilogues
template<int MODE>
__global__ __launch_bounds__(256) void gemm_bt(
    const __bf16* __restrict__ A, const __bf16* __restrict__ Bt,
    const float* __restrict__ bias, const float* __restrict__ resid,
    float* __restrict__ outF, __bf16* __restrict__ outB,
    __bf16* __restrict__ qO, __bf16* __restrict__ kO, __bf16* __restrict__ vtO,
    int M, int N, int K)
{
  __shared__ __align__(16) __bf16 As[128*32];
  __shared__ __align__(16) __bf16 Bs[128*32];
  const int tid = threadIdx.x;
  const int lane = tid & 63, wave = tid >> 6;
  const int wr = wave >> 1, wc = wave & 1;
  const int l15 = lane & 15, lg = lane >> 4;
  const int bm = blockIdx.x, bn = blockIdx.y;
  const __bf16* Ab = A  + (size_t)bm*128*K;
  const __bf16* Bb = Bt + (size_t)bn*128*K;
  f32x4 acc[4][4] = {};
  const int r0 = tid >> 2;
  const int c0 = (tid & 3) * 8;
  char* lA0 = (char*)As + wave*1024;
  char* lA1 = (char*)As + 4096 + wave*1024;
  char* lB0 = (char*)Bs + wave*1024;
  char* lB1 = (char*)Bs + 4096 + wave*1024;
  const int nk = K >> 5;
  for (int kt = 0; kt < nk; ++kt){
    __syncthreads();
    const int k0 = kt*32;
    gld_lds16(Ab + (size_t)r0*K      + k0 + c0, lA0);
    gld_lds16(Ab + (size_t)(r0+64)*K + k0 + c0, lA1);
    gld_lds16(Bb + (size_t)r0*K      + k0 + c0, lB0);
    gld_lds16(Bb + (size_t)(r0+64)*K + k0 + c0, lB1);
    __syncthreads();
    bf16x8 af[4], bfv[4];
    #pragma unroll
    for (int i=0;i<4;++i){
      af[i]  = *(const bf16x8*)&As[(wr*64 + i*16 + l15)*32 + lg*8];
      bfv[i] = *(const bf16x8*)&Bs[(wc*64 + i*16 + l15)*32 + lg*8];
    }
    #pragma unroll
    for (int i=0;i<4;++i)
      #pragma unroll
      for (int j=0;j<4;++j)
        acc[i][j] = __builtin_amdgcn_mfma_f32_16x16x32_bf16(af[i], bfv[j], acc[i][j], 0,0,0);
  }
  #pragma unroll
  for (int i=0;i<4;++i){
    #pragma unroll
    for (int j=0;j<4;++j){
      const int col = bn*128 + wc*64 + j*16 + l15;
      float bv;
      if constexpr (MODE==2) bv = 0.f; else bv = bias[col];
      #pragma unroll
      for (int r=0;r<4;++r){
        const int row = bm*128 + wr*64 + i*16 + lg*4 + r;
        float v = acc[i][j][r] + bv;
        if constexpr (MODE==0){
          const int b_ = row >> 11, s_ = row & 2047;
          if (col < 1024){
            const int h = col>>6, d = col&63;
            qO[((size_t)(b_*16+h)*2048 + s_)*64 + d] = (__bf16)v;
          } else if (col < 2048){
            const int h = (col-1024)>>6, d = (col-1024)&63;
            kO[((size_t)(b_*16+h)*2048 + s_)*64 + d] = (__bf16)v;
          } else {
            const int h = (col-2048)>>6, d = (col-2048)&63;
            vtO[((size_t)(b_*16+h)*64 + d)*2048 + s_] = (__bf16)v;
          }
        } else if constexpr (MODE==1){
          outF[(size_t)row*N + col] = v + resid[(size_t)row*N + col];
        } else {
          const float gl = 0.5f*v*(1.f + erff(v*0.70710678118f));
          outB[(size_t)row*N + col] = (__bf16)gl;
        }
      }
    }
  }
}

// ---------------- flash attention v4, causal, 32x32 MFMA + in-register softmax.
// Block: 256 threads / 4 waves, 128 q-rows (32/wave). KVBLK=64, double-buffered LDS,
// stage-before-compute. Swapped QK^T: lane owns full P-row for q=lane&31.
// Q,K: [bh][s][64] bf16 ; Vt: [bh][64][s] bf16 ; out: [b*2048+s][h*64+d] bf16
__global__ __launch_bounds__(256, 2) void attn_kernel(
    const __bf16* __restrict__ Q, const __bf16* __restrict__ K,
    const __bf16* __restrict__ Vt, __bf16* __restrict__ out)
{
  __shared__ __align__(16) __bf16 Ks[2][64*64];
  __shared__ __align__(16) __bf16 Vs[2][64*64];
  const int tid = threadIdx.x;
  const int lane = tid & 63, wave = tid >> 6;
  const int l31 = lane & 31, hi = lane >> 5;
  const int bh = blockIdx.y;
  const int qblk = (int)(gridDim.x - 1) - blockIdx.x;   // longest blocks first
  const int qb = qblk * 128;
  const int qw = qb + wave*32;                          // wave's first q-row
  const __bf16* Qh = Q + (size_t)bh*2048*64;
  const char*  Khc = (const char*)(K  + (size_t)bh*2048*64);
  const char*  Vhc = (const char*)(Vt + (size_t)bh*64*2048);

  // Q as B-operand: qf[s] elem j = Q[qw+l31][s*16 + hi*8 + j], pre-scaled by 0.125
  bf16x8 qf[4];
  #pragma unroll
  for (int s4=0;s4<4;++s4){
    bf16x8 t8 = *(const bf16x8*)&Qh[(size_t)(qw + l31)*64 + s4*16 + hi*8];
    #pragma unroll
    for (int j=0;j<8;++j) t8[j] = (__bf16)((float)t8[j] * 0.125f);
    qf[s4] = t8;
  }

  f32x16 oacc[2] = {};
  float mrun = -1e30f, lrun = 0.f;

  const int swz_st = (((lane&7) ^ (lane>>3)) << 4);     // staging source swizzle
  const int rswz = ((l31 & 7) << 4);                    // read-side swizzle
  const int nst = qblk*2 + 2;

  // prologue: stage tile 0 into buffer 0
  #pragma unroll
  for (int i=0;i<2;++i){
    const int rl = wave*16 + i*8 + (lane>>3);
    gld_lds16(Khc + (size_t)rl*128 + swz_st,  (char*)&Ks[0][0] + wave*2048 + i*1024);
    gld_lds16(Vhc + (size_t)rl*4096 + swz_st, (char*)&Vs[0][0] + wave*2048 + i*1024);
  }
  __syncthreads();

  for (int st = 0; st < nst; ++st){
    const int cur = st & 1;
    const int kv0 = st*64;
    if (st+1 < nst){
      const size_t nkv0 = (size_t)(kv0 + 64);
      #pragma unroll
      for (int i=0;i<2;++i){
        const int rl = wave*16 + i*8 + (lane>>3);
        gld_lds16(Khc + (nkv0 + rl)*128 + swz_st,              (char*)&Ks[cur^1][0] + wave*2048 + i*1024);
        gld_lds16(Vhc + (size_t)rl*4096 + nkv0*2 + swz_st,     (char*)&Vs[cur^1][0] + wave*2048 + i*1024);
      }
    }
    if (kv0 <= qw + 31){                                // wave-uniform; else fully masked
      const char* Kb = (const char*)&Ks[cur][0];
      const char* Vb = (const char*)&Vs[cur][0];
      // QK^T swapped: s0/s1 = D[kv_local][q], kv = kv0 + {0,32} + (r&3)+8*(r>>2)+4*hi
      f32x16 s0 = {}, s1 = {};
      __builtin_amdgcn_s_setprio(1);
      #pragma unroll
      for (int s4=0;s4<4;++s4){
        bf16x8 k0 = *(const bf16x8*)(Kb + l31*128      + ((s4*32 + hi*16) ^ rswz));
        bf16x8 k1 = *(const bf16x8*)(Kb + (32+l31)*128 + ((s4*32 + hi*16) ^ rswz));
        s0 = __builtin_amdgcn_mfma_f32_32x32x16_bf16(k0, qf[s4], s0, 0,0,0);
        s1 = __builtin_amdgcn_mfma_f32_32x32x16_bf16(k1, qf[s4], s1, 0,0,0);
      }
      __builtin_amdgcn_s_setprio(0);
      // causal mask (boundary steps only)
      if (kv0 + 63 > qw){
        const int q = qw + l31;
        #pragma unroll
        for (int r=0;r<16;++r){
          const int kvA = kv0 + (r&3) + 8*(r>>2) + 4*hi;
          if (kvA      > q) s0[r] = -1e30f;
          if (kvA + 32 > q) s1[r] = -1e30f;
        }
      }
      // in-lane row max (32 vals) + cross-half combine
      f32x16 mm;
      #pragma unroll
      for (int r=0;r<16;++r) mm[r] = fmaxf(s0[r], s1[r]);
      #pragma unroll
      for (int w=8; w>0; w>>=1)
        #pragma unroll
        for (int r=0;r<8;++r) if (r<w) mm[r] = fmaxf(mm[r], mm[r+w]);
      float mx = fmaxf(mm[0], __shfl_xor(mm[0], 32));
      // defer-max (T13): rescale only when max grew past threshold
      if (!__all(mx <= mrun + 8.0f)){
        const float nm = fmaxf(mrun, mx);
        const float co = exp2f((mrun - nm) * 1.44269504f);
        lrun *= co;
        #pragma unroll
        for (int r=0;r<16;++r){ oacc[0][r] *= co; oacc[1][r] *= co; }
        mrun = nm;
      }
      const float mb = mrun * 1.44269504f;
      #pragma unroll
      for (int r=0;r<16;++r){
        s0[r] = exp2f(s0[r]*1.44269504f - mb);
        s1[r] = exp2f(s1[r]*1.44269504f - mb);
      }
      // row sum
      f32x16 ss;
      #pragma unroll
      for (int r=0;r<16;++r) ss[r] = s0[r] + s1[r];
      #pragma unroll
      for (int w=8; w>0; w>>=1)
        #pragma unroll
        for (int r=0;r<8;++r) if (r<w) ss[r] += ss[r+w];
      lrun += ss[0] + __shfl_xor(ss[0], 32);
      // T12: pack P to bf16 words + cross-half exchange -> PV B-frags
      // pb[ks] elem j = P[q][kv0 + ks*16 + hi*8 + j]
      bf16x8 pb[4];
      #pragma unroll
      for (int kt=0; kt<2; ++kt){
        const f32x16 sv = kt ? s1 : s0;
        unsigned wa[4], wb[4];
        #pragma unroll
        for (int m=0;m<4;++m){
          union { __bf16 h[2]; unsigned u; } A_, B_;
          A_.h[0] = (__bf16)sv[4*m+0]; A_.h[1] = (__bf16)sv[4*m+1];
          B_.h[0] = (__bf16)sv[4*m+2]; B_.h[1] = (__bf16)sv[4*m+3];
          wa[m] = A_.u; wb[m] = B_.u;
        }
        #pragma unroll
        for (int half=0; half<2; ++half){
          const int mp = half*2;
          const unsigned own_a  = hi ? wa[mp+1] : wa[mp+0];
          const unsigned sent_a = hi ? wa[mp+0] : wa[mp+1];
          const unsigned own_b  = hi ? wb[mp+1] : wb[mp+0];
          const unsigned sent_b = hi ? wb[mp+0] : wb[mp+1];
          const unsigned recv_a = (unsigned)__shfl_xor((int)sent_a, 32);
          const unsigned recv_b = (unsigned)__shfl_xor((int)sent_b, 32);
          union { unsigned u[4]; bf16x8 v; } F;
          F.u[0] = hi ? recv_a : own_a;
          F.u[1] = hi ? recv_b : own_b;
          F.u[2] = hi ? own_a : recv_a;
          F.u[3] = hi ? own_b : recv_b;
          pb[kt*2 + half] = F.v;
        }
      }
      // PV swapped: oacc[dt] = D[d_local][q] += Vt-frag x P-frag
      __builtin_amdgcn_s_setprio(1);
      #pragma unroll
      for (int ks=0; ks<4; ++ks){
        bf16x8 v0 = *(const bf16x8*)(Vb + l31*128      + ((ks*32 + hi*16) ^ rswz));
        bf16x8 v1 = *(const bf16x8*)(Vb + (32+l31)*128 + ((ks*32 + hi*16) ^ rswz));
        oacc[0] = __builtin_amdgcn_mfma_f32_32x32x16_bf16(v0, pb[ks], oacc[0], 0,0,0);
        oacc[1] = __builtin_amdgcn_mfma_f32_32x32x16_bf16(v1, pb[ks], oacc[1], 0,0,0);
      }
      __builtin_amdgcn_s_setprio(0);
    }
    __syncthreads();   // drains vmcnt(0): next tile ready; all waves done with cur
  }

  // epilogue: bounce O through LDS (reuse Ks) for coalesced bf16 stores
  const float invl = 1.0f / lrun;
  char* Ob = (char*)&Ks[0][0] + wave*4096;    // per-wave 32q x 64d bf16 (swizzled)
  #pragma unroll
  for (int dt=0; dt<2; ++dt)
    #pragma unroll
    for (int m=0; m<4; ++m)
      #pragma unroll
      for (int e=0; e<4; e+=2){
        union { __bf16 h[2]; unsigned u; } p2;
        p2.h[0] = (__bf16)(oacc[dt][4*m+e]   * invl);
        p2.h[1] = (__bf16)(oacc[dt][4*m+e+1] * invl);
        *(unsigned*)(Ob + l31*128 + ((dt*64 + m*16 + hi*8 + e*2) ^ rswz)) = p2.u;
      }
  const int b_ = bh >> 4, h_ = bh & 15;
  const int l15 = lane & 15, lg4 = lane >> 4;
  #pragma unroll
  for (int g=0; g<8; ++g){
    const int ql = g*4 + lg4;
    uint2 v = *(uint2*)(Ob + ql*128 + ((l15*8) ^ ((ql&7)<<4)));
    *(uint2*)&out[((size_t)(b_*2048 + qw + ql))*1024 + h_*64 + l15*4] = v;
  }
}

extern "C" void kernel_launch(void* const* d_in, const int* in_sizes, int n_in,
                              void* d_out, int out_size, void* d_ws, size_t ws_size,
                              hipStream_t stream) {
  const float* x      = (const float*)d_in[0];
  const float* ln1_g  = (const float*)d_in[1];
  const float* ln1_b  = (const float*)d_in[2];
  const float* w_qkv  = (const float*)d_in[3];
  const float* b_qkv  = (const float*)d_in[4];
  const float* w_dense= (const float*)d_in[5];
  const float* b_dense= (const float*)d_in[6];
  const float* ln2_g  = (const float*)d_in[7];
  const float* ln2_b  = (const float*)d_in[8];
  const float* w_fc1  = (const float*)d_in[9];
  const float* w_fc2  = (const float*)d_in[10];
  const float* b_fc2  = (const float*)d_in[11];

  char* ws = (char*)d_ws;
  __bf16* wqkvT  = (__bf16*)(ws + 0);          // [3072][1024]  6 MB
  __bf16* wdenT  = (__bf16*)(ws + 6291456);    // [1024][1024]  2 MB
  __bf16* wfc1T  = (__bf16*)(ws + 8388608);    // [2048][1024]  4 MB
  __bf16* wfc2T  = (__bf16*)(ws + 12582912);   // [1024][2048]  4 MB
  __bf16* xn     = (__bf16*)(ws + 16777216);   // [4096][1024]  8 MB
  __bf16* Qb     = (__bf16*)(ws + 25165824);   // [32][2048][64] 8 MB
  __bf16* Kb     = (__bf16*)(ws + 33554432);   // [32][2048][64] 8 MB
  __bf16* Vtb    = (__bf16*)(ws + 41943040);   // [32][64][2048] 8 MB
  __bf16* attnb  = (__bf16*)(ws + 50331648);   // [4096][1024]  8 MB
  float*  outf   = (float*) (ws + 58720256);   // [4096][1024] 16 MB
  __bf16* mb     = (__bf16*)(ws + 75497472);   // [4096][1024]  8 MB
  __bf16* h1b    = (__bf16*)(ws + 83886080);   // [4096][2048] 16 MB

  dim3 blkT(32,8);
  transpose_cvt<<<dim3(3072/32, 1024/32), blkT, 0, stream>>>(w_qkv,   wqkvT, 1024, 3072);
  transpose_cvt<<<dim3(1024/32, 1024/32), blkT, 0, stream>>>(w_dense, wdenT, 1024, 1024);
  transpose_cvt<<<dim3(2048/32, 1024/32), blkT, 0, stream>>>(w_fc1,   wfc1T, 1024, 2048);
  transpose_cvt<<<dim3(1024/32, 2048/32), blkT, 0, stream>>>(w_fc2,   wfc2T, 2048, 1024);
  ln_kernel<<<4096, 256, 0, stream>>>(x, ln1_g, ln1_b, xn);
  gemm_bt<0><<<dim3(32,24), 256, 0, stream>>>(xn, wqkvT, b_qkv, nullptr,
                                              nullptr, nullptr, Qb, Kb, Vtb, 4096, 3072, 1024);
  attn_kernel<<<dim3(16,32), 256, 0, stream>>>(Qb, Kb, Vtb, attnb);
  gemm_bt<1><<<dim3(32,8), 256, 0, stream>>>(attnb, wdenT, b_dense, x,
                                             outf, nullptr, nullptr, nullptr, nullptr, 4096, 1024, 1024);
  ln_kernel<<<4096, 256, 0, stream>>>(outf, ln2_g, ln2_b, mb);
  gemm_bt<2><<<dim3(32,16), 256, 0, stream>>>(mb, wfc1T, nullptr, nullptr,
                                              nullptr, h1b, nullptr, nullptr, nullptr, 4096, 2048, 1024);
  gemm_bt<1><<<dim3(32,8), 256, 0, stream>>>(h1b, wfc2T, b_fc2, outf,
                                             (float*)d_out, nullptr, nullptr, nullptr, nullptr, 4096, 1024, 2048);
}